// Round 3
// baseline (406.641 us; speedup 1.0000x reference)
//
#include <hip/hip_runtime.h>

// GraphSAGE 2-layer. N=50000, E=800000, 128 -> 256 -> 256.
// Round 12: fuse gather1 + mfma1. The layer-1 gather's FETCH (175MB) is at its
// compulsory per-XCD floor and fabric-capped (~3.8 TB/s); the win is removing
// everything serialized around it: aggb round-trip (25MB write + 51MB read),
// the double A-read of the N-split mfma grid, and one launch barrier. Fused
// kernel: 391 blocks x 512 thr; phase1 gathers the block's 128 rows into a
// 64KB XOR-swizzled LDS tile; phase2 does 128x256 MFMA with A=[LDS agg |
// global self rows], B-frags direct from L2-resident Bt1. Layer 0 unchanged.

#define NN 50000
#define NE 800000

typedef __bf16 v8bf __attribute__((ext_vector_type(8)));
typedef float v4f __attribute__((ext_vector_type(4)));
typedef float nf4 __attribute__((ext_vector_type(4)));
typedef unsigned nu2 __attribute__((ext_vector_type(2)));

__device__ __forceinline__ unsigned short f2b(float f) {
    unsigned u = __float_as_uint(f);
    return (unsigned short)((u + 0x7FFFu + ((u >> 16) & 1u)) >> 16);
}
__device__ __forceinline__ float b2f(unsigned short h) {
    return __uint_as_float(((unsigned)h) << 16);
}
__device__ __forceinline__ unsigned pack2(float a, float b) {
    return (unsigned)f2b(a) | ((unsigned)f2b(b) << 16);
}

// Fused hist + prep. Sections by blockIdx (256 threads each), hist FIRST so
// its atomic-bound phase overlaps the streaming casts behind it:
//   [0,782)            hist: cnt[dst]++ and rank[e] = old count. 1024 e/blk.
//   [782,1038)         Bt0 cast
//   [1038,1550)        Bt1 cast
//   [1550,7800)        x -> bf16 (1.6M float4)
#define PH_HIST 782
#define PH_BT0 256
#define PH_BT1 512
#define PH_XB  6250
__global__ __launch_bounds__(256) void k_preph(const float* __restrict__ x,
                                               const float* __restrict__ Wl0,
                                               const float* __restrict__ Wr0,
                                               const float* __restrict__ Wl1,
                                               const float* __restrict__ Wr1,
                                               const int* __restrict__ dst,
                                               int* __restrict__ cnt,
                                               int* __restrict__ rank,
                                               unsigned short* __restrict__ Bt0,
                                               unsigned short* __restrict__ Bt1,
                                               unsigned short* __restrict__ xb) {
    int b = blockIdx.x;
    int tid = threadIdx.x;
    if (b < PH_HIST) {
        int e = b * 1024 + tid;                         // 4 edges/thread, stride 256
        if (e + 768 < NE) {
            int d0 = __builtin_nontemporal_load(dst + e);
            int d1 = __builtin_nontemporal_load(dst + e + 256);
            int d2 = __builtin_nontemporal_load(dst + e + 512);
            int d3 = __builtin_nontemporal_load(dst + e + 768);
            int p0 = atomicAdd(&cnt[d0], 1);
            int p1 = atomicAdd(&cnt[d1], 1);
            int p2 = atomicAdd(&cnt[d2], 1);
            int p3 = atomicAdd(&cnt[d3], 1);
            __builtin_nontemporal_store(p0, rank + e);
            __builtin_nontemporal_store(p1, rank + e + 256);
            __builtin_nontemporal_store(p2, rank + e + 512);
            __builtin_nontemporal_store(p3, rank + e + 768);
        } else {
#pragma unroll
            for (int i = 0; i < 4; ++i) {
                int ee = e + i * 256;
                if (ee < NE) {
                    int d = __builtin_nontemporal_load(dst + ee);
                    int pos = atomicAdd(&cnt[d], 1);
                    __builtin_nontemporal_store(pos, rank + ee);
                }
            }
        }
    } else if (b < PH_HIST + PH_BT0) {
        int idx = (b - PH_HIST) * 256 + tid;            // [0, 65536)
        int n = idx >> 8, k = idx & 255;
        float v = (k < 128) ? Wl0[(size_t)k * 256 + n] : Wr0[(size_t)(k - 128) * 256 + n];
        Bt0[idx] = f2b(v);
    } else if (b < PH_HIST + PH_BT0 + PH_BT1) {
        int idx = (b - PH_HIST - PH_BT0) * 256 + tid;   // [0, 131072)
        int n = idx >> 9, k = idx & 511;
        float v = (k < 256) ? Wl1[(size_t)k * 256 + n] : Wr1[(size_t)(k - 256) * 256 + n];
        Bt1[idx] = f2b(v);
    } else {
        int i4 = (b - PH_HIST - PH_BT0 - PH_BT1) * 256 + tid;  // [0, 1.6M)
        nf4 v = __builtin_nontemporal_load((const nf4*)x + i4);
        nu2 o;
        o.x = pack2(v.x, v.y);
        o.y = pack2(v.z, v.w);
        *((nu2*)xb + i4) = o;
    }
}

// Fused scan: 49 blocks x 1024. Per-block LDS scan; chunk sums published via
// atomicExch flags (value+1), thread 0 spin-accumulates earlier chunks.
// 49 blocks <= 256 CUs: all co-resident.
__global__ __launch_bounds__(1024) void k_scanf(const int* __restrict__ cnt,
                                                int* __restrict__ bsum,
                                                int* __restrict__ rp,
                                                float* __restrict__ dinv) {
    __shared__ int tmp[1024];
    __shared__ int s_off;
    const int b = blockIdx.x, tid = threadIdx.x;
    const int gid = b * 1024 + tid;
    int v = (gid < NN) ? cnt[gid] : 0;
    tmp[tid] = v;
    __syncthreads();
    for (int off = 1; off < 1024; off <<= 1) {
        int t = (tid >= off) ? tmp[tid - off] : 0;
        __syncthreads();
        tmp[tid] += t;
        __syncthreads();
    }
    if (tid == 1023) atomicExch(&bsum[b], tmp[1023] + 1);   // publish (nonzero)
    if (tid == 0) {
        int off = 0;
        for (int i = 0; i < b; ++i) {
            int val;
            while ((val = atomicAdd(&bsum[i], 0)) == 0) {}
            off += val - 1;
        }
        s_off = off;
    }
    __syncthreads();
    if (gid < NN) {
        rp[gid] = tmp[tid] - v + s_off;
        dinv[gid] = 1.0f / fmaxf((float)v, 1.0f);
    }
    if (gid == 0) rp[NN] = NE;
}

// Atomic-free bucket: pos = rp[dst] + rank. 4 edges/thread, ILP.
__global__ __launch_bounds__(256) void k_bucket(const int* __restrict__ src,
                                                const int* __restrict__ dst,
                                                const float* __restrict__ ew,
                                                const int* __restrict__ rank,
                                                const int* __restrict__ rp,
                                                int2* __restrict__ epk) {
    int base = blockIdx.x * 1024 + threadIdx.x;
#pragma unroll
    for (int i = 0; i < 4; ++i) {
        int e = base + i * 256;
        if (e < NE) {
            int d = __builtin_nontemporal_load(dst + e);
            int r = __builtin_nontemporal_load(rank + e);
            int s = __builtin_nontemporal_load(src + e);
            float w = __builtin_nontemporal_load(ew + e);
            epk[rp[d] + r] = make_int2(s, __float_as_int(w));
        }
    }
}

// gather0: xb bf16 [NN][128] -> aggb bf16 [NN][128] (scaled by dinv).
// 1 wave/node; edge metadata batch-loaded (lane L holds epk[b+L]) + shfl.
// 8-edge batches: 8 independent row loads in flight per wave.
__global__ __launch_bounds__(256) void k_gather0(const unsigned short* __restrict__ xb,
                                                 const int* __restrict__ rp,
                                                 const int2* __restrict__ epk,
                                                 const float* __restrict__ dinv,
                                                 unsigned short* __restrict__ aggb) {
    int wid = (blockIdx.x * 256 + threadIdx.x) >> 6;
    int lane = threadIdx.x & 63;
    if (wid >= NN) return;
    int beg = rp[wid], end = rp[wid + 1];
    float di = dinv[wid];
    float ax = 0.f, ay = 0.f;
    for (int b = beg; b < end; b += 64) {
        int n = min(end - b, 64);
        int2 pk = epk[b + min(lane, n - 1)];
        int j = 0;
        for (; j + 7 < n; j += 8) {
            int s[8];
#pragma unroll
            for (int i = 0; i < 8; ++i) s[i] = __shfl(pk.x, j + i);
            unsigned u[8];
#pragma unroll
            for (int i = 0; i < 8; ++i)
                u[i] = *(const unsigned*)(xb + (size_t)s[i] * 128 + lane * 2);
            float w[8];
#pragma unroll
            for (int i = 0; i < 8; ++i) w[i] = __int_as_float(__shfl(pk.y, j + i));
#pragma unroll
            for (int i = 0; i < 8; ++i) {
                ax += w[i] * b2f((unsigned short)(u[i] & 0xFFFF));
                ay += w[i] * b2f((unsigned short)(u[i] >> 16));
            }
        }
        for (; j + 3 < n; j += 4) {
            int s0 = __shfl(pk.x, j + 0), s1 = __shfl(pk.x, j + 1);
            int s2 = __shfl(pk.x, j + 2), s3 = __shfl(pk.x, j + 3);
            unsigned u0 = *(const unsigned*)(xb + (size_t)s0 * 128 + lane * 2);
            unsigned u1 = *(const unsigned*)(xb + (size_t)s1 * 128 + lane * 2);
            unsigned u2 = *(const unsigned*)(xb + (size_t)s2 * 128 + lane * 2);
            unsigned u3 = *(const unsigned*)(xb + (size_t)s3 * 128 + lane * 2);
            float w0 = __int_as_float(__shfl(pk.y, j + 0));
            float w1 = __int_as_float(__shfl(pk.y, j + 1));
            float w2 = __int_as_float(__shfl(pk.y, j + 2));
            float w3 = __int_as_float(__shfl(pk.y, j + 3));
            ax += w0 * b2f((unsigned short)(u0 & 0xFFFF)) + w1 * b2f((unsigned short)(u1 & 0xFFFF))
                + w2 * b2f((unsigned short)(u2 & 0xFFFF)) + w3 * b2f((unsigned short)(u3 & 0xFFFF));
            ay += w0 * b2f((unsigned short)(u0 >> 16)) + w1 * b2f((unsigned short)(u1 >> 16))
                + w2 * b2f((unsigned short)(u2 >> 16)) + w3 * b2f((unsigned short)(u3 >> 16));
        }
        for (; j < n; ++j) {
            int s = __shfl(pk.x, j);
            float w = __int_as_float(__shfl(pk.y, j));
            unsigned u = *(const unsigned*)(xb + (size_t)s * 128 + lane * 2);
            ax += w * b2f((unsigned short)(u & 0xFFFF));
            ay += w * b2f((unsigned short)(u >> 16));
        }
    }
    __builtin_nontemporal_store(pack2(ax * di, ay * di),
                                (unsigned*)(aggb + (size_t)wid * 128 + lane * 2));
}

// MFMA GEMM (layer 0): C = concat(Aagg, Aself) @ Bt^T + bias.
// 128x128 tile per block, 4 waves (2x2), 4x4 MFMA 16x16x32 per wave. bf16 in.
template <int K0, bool OUT_F32, bool RELU>
__global__ __launch_bounds__(256) void k_mfma(const unsigned short* __restrict__ Aagg,
                                              const unsigned short* __restrict__ Aself,
                                              const unsigned short* __restrict__ Bt,
                                              const float* __restrict__ bias,
                                              void* __restrict__ outp) {
    __shared__ unsigned short As[128 * 32];
    __shared__ unsigned short Bs[128 * 32];
    const int tid = threadIdx.x;
    const int m0 = blockIdx.x * 128;
    const int n0 = blockIdx.y * 128;
    const int K = 2 * K0;
    const int lane = tid & 63;
    const int w = tid >> 6;
    const int wr = w >> 1, wc = w & 1;
    const int fr = lane & 15, fq = lane >> 4;
    const int srow = tid >> 2;
    const int schunk = (tid & 3) * 8;

    v4f acc[4][4];
#pragma unroll
    for (int mi = 0; mi < 4; ++mi)
#pragma unroll
        for (int ni = 0; ni < 4; ++ni)
            acc[mi][ni] = (v4f){0.f, 0.f, 0.f, 0.f};

    for (int k0 = 0; k0 < K; k0 += 32) {
        const int kk = k0 + schunk;
        const int r0 = m0 + srow, r1 = m0 + srow + 64;
        uint4 av0 = make_uint4(0, 0, 0, 0), av1 = make_uint4(0, 0, 0, 0);
        const unsigned short* Asrc = (kk < K0) ? Aagg : (Aself - K0);
        if (r0 < NN) av0 = *(const uint4*)(Asrc + (size_t)r0 * K0 + kk);
        if (r1 < NN) av1 = *(const uint4*)(Asrc + (size_t)r1 * K0 + kk);
        uint4 bv0 = *(const uint4*)(Bt + (size_t)(n0 + srow) * K + kk);
        uint4 bv1 = *(const uint4*)(Bt + (size_t)(n0 + srow + 64) * K + kk);

        __syncthreads();
        *(uint4*)(As + srow * 32 + schunk) = av0;
        *(uint4*)(As + (srow + 64) * 32 + schunk) = av1;
        *(uint4*)(Bs + srow * 32 + schunk) = bv0;
        *(uint4*)(Bs + (srow + 64) * 32 + schunk) = bv1;
        __syncthreads();

        v8bf a[4], b[4];
#pragma unroll
        for (int mi = 0; mi < 4; ++mi)
            a[mi] = *(const v8bf*)(As + (wr * 64 + mi * 16 + fr) * 32 + fq * 8);
#pragma unroll
        for (int ni = 0; ni < 4; ++ni)
            b[ni] = *(const v8bf*)(Bs + (wc * 64 + ni * 16 + fr) * 32 + fq * 8);
#pragma unroll
        for (int mi = 0; mi < 4; ++mi)
#pragma unroll
            for (int ni = 0; ni < 4; ++ni)
                acc[mi][ni] = __builtin_amdgcn_mfma_f32_16x16x32_bf16(a[mi], b[ni], acc[mi][ni], 0, 0, 0);
    }

#pragma unroll
    for (int mi = 0; mi < 4; ++mi) {
#pragma unroll
        for (int ni = 0; ni < 4; ++ni) {
            const int col = n0 + wc * 64 + ni * 16 + fr;
            const float bb = bias[col];
#pragma unroll
            for (int r = 0; r < 4; ++r) {
                const int row = m0 + wr * 64 + mi * 16 + fq * 4 + r;
                if (row < NN) {
                    float v = acc[mi][ni][r] + bb;
                    if (RELU) v = fmaxf(v, 0.f);
                    if (OUT_F32)
                        __builtin_nontemporal_store(v, &((float*)outp)[(size_t)row * 256 + col]);
                    else
                        ((unsigned short*)outp)[(size_t)row * 256 + col] = f2b(v);
                }
            }
        }
    }
}

// Fused layer 1: gather (h1b -> LDS agg tile, XOR-swizzled) + 128x256 MFMA.
// 391 blocks x 512 threads (8 waves). Phase 1: wave w gathers rows
// [w*16, w*16+16) of the block's 128-node tile into aggS (bf16, swizzle
// byte ^= (row&7)<<4 to kill the 512B-stride bank conflict on a-frag reads).
// Phase 2: waves 4M x 2N, each 32x128 output; A k<256 from aggS, k>=256 from
// global self rows (read once, contiguous); B-frags direct from L2-hot Bt1.
__global__ __launch_bounds__(512) void k_fused1(const unsigned short* __restrict__ h,
                                                const int* __restrict__ rp,
                                                const int2* __restrict__ epk,
                                                const float* __restrict__ dinv,
                                                const unsigned short* __restrict__ Bt,
                                                const float* __restrict__ bias,
                                                float* __restrict__ out) {
    __shared__ unsigned short aggS[128 * 256];   // 64 KB
    const int tid = threadIdx.x;
    const int w = tid >> 6, lane = tid & 63;
    const int m0 = blockIdx.x * 128;

    // ---------------- phase 1: gather ----------------
    for (int i = 0; i < 16; ++i) {
        const int row = w * 16 + i;
        const int wid = m0 + row;
        float a0 = 0.f, a1 = 0.f, a2 = 0.f, a3 = 0.f;
        if (wid < NN) {
            const int beg = rp[wid], end = rp[wid + 1];
            const float di = dinv[wid];
            for (int eb = beg; eb < end; eb += 64) {
                int n = min(end - eb, 64);
                int2 pk = epk[eb + min(lane, n - 1)];
                int j = 0;
                for (; j + 7 < n; j += 8) {
                    int s[8];
#pragma unroll
                    for (int q = 0; q < 8; ++q) s[q] = __shfl(pk.x, j + q);
                    uint2 u[8];
#pragma unroll
                    for (int q = 0; q < 8; ++q)
                        u[q] = *(const uint2*)(h + (size_t)s[q] * 256 + lane * 4);
                    float wt[8];
#pragma unroll
                    for (int q = 0; q < 8; ++q) wt[q] = __int_as_float(__shfl(pk.y, j + q));
#pragma unroll
                    for (int q = 0; q < 8; ++q) {
                        a0 += wt[q] * b2f((unsigned short)(u[q].x & 0xFFFF));
                        a1 += wt[q] * b2f((unsigned short)(u[q].x >> 16));
                        a2 += wt[q] * b2f((unsigned short)(u[q].y & 0xFFFF));
                        a3 += wt[q] * b2f((unsigned short)(u[q].y >> 16));
                    }
                }
                for (; j < n; ++j) {
                    int s = __shfl(pk.x, j);
                    float wt = __int_as_float(__shfl(pk.y, j));
                    uint2 u = *(const uint2*)(h + (size_t)s * 256 + lane * 4);
                    a0 += wt * b2f((unsigned short)(u.x & 0xFFFF));
                    a1 += wt * b2f((unsigned short)(u.x >> 16));
                    a2 += wt * b2f((unsigned short)(u.y & 0xFFFF));
                    a3 += wt * b2f((unsigned short)(u.y >> 16));
                }
            }
            a0 *= di; a1 *= di; a2 *= di; a3 *= di;
        }
        unsigned off = ((unsigned)(row * 512 + lane * 8)) ^ ((unsigned)((row & 7) << 4));
        nu2 o;
        o.x = pack2(a0, a1);
        o.y = pack2(a2, a3);
        *(nu2*)((char*)aggS + off) = o;
    }
    __syncthreads();

    // ---------------- phase 2: MFMA 128x256, K=512 ----------------
    const int wr = w >> 1, wc = w & 1;          // 4 M-waves x 2 N-waves
    const int fr = lane & 15, fq = lane >> 4;
    v4f acc[2][8];
#pragma unroll
    for (int mi = 0; mi < 2; ++mi)
#pragma unroll
        for (int ni = 0; ni < 8; ++ni)
            acc[mi][ni] = (v4f){0.f, 0.f, 0.f, 0.f};

    // k in [0,256): A from LDS agg tile
#pragma unroll
    for (int ks = 0; ks < 8; ++ks) {
        v8bf a[2], b[8];
#pragma unroll
        for (int mi = 0; mi < 2; ++mi) {
            const int r = wr * 32 + mi * 16 + fr;
            unsigned off = ((unsigned)(r * 512 + ks * 64 + fq * 16)) ^ ((unsigned)((r & 7) << 4));
            a[mi] = *(const v8bf*)((const char*)aggS + off);
        }
#pragma unroll
        for (int ni = 0; ni < 8; ++ni) {
            const int col = wc * 128 + ni * 16 + fr;
            b[ni] = *(const v8bf*)(Bt + (size_t)col * 512 + ks * 32 + fq * 8);
        }
#pragma unroll
        for (int mi = 0; mi < 2; ++mi)
#pragma unroll
            for (int ni = 0; ni < 8; ++ni)
                acc[mi][ni] = __builtin_amdgcn_mfma_f32_16x16x32_bf16(a[mi], b[ni], acc[mi][ni], 0, 0, 0);
    }

    // k in [256,512): A = self rows from global h
#pragma unroll
    for (int ks = 0; ks < 8; ++ks) {
        v8bf a[2], b[8];
#pragma unroll
        for (int mi = 0; mi < 2; ++mi) {
            const int r = m0 + wr * 32 + mi * 16 + fr;
            uint4 t = make_uint4(0, 0, 0, 0);
            if (r < NN) t = *(const uint4*)(h + (size_t)r * 256 + ks * 32 + fq * 8);
            a[mi] = *(const v8bf*)&t;
        }
#pragma unroll
        for (int ni = 0; ni < 8; ++ni) {
            const int col = wc * 128 + ni * 16 + fr;
            b[ni] = *(const v8bf*)(Bt + (size_t)col * 512 + 256 + ks * 32 + fq * 8);
        }
#pragma unroll
        for (int mi = 0; mi < 2; ++mi)
#pragma unroll
            for (int ni = 0; ni < 8; ++ni)
                acc[mi][ni] = __builtin_amdgcn_mfma_f32_16x16x32_bf16(a[mi], b[ni], acc[mi][ni], 0, 0, 0);
    }

    // epilogue
#pragma unroll
    for (int mi = 0; mi < 2; ++mi) {
#pragma unroll
        for (int ni = 0; ni < 8; ++ni) {
            const int col = wc * 128 + ni * 16 + fr;
            const float bb = bias[col];
#pragma unroll
            for (int r = 0; r < 4; ++r) {
                const int row = m0 + wr * 32 + mi * 16 + fq * 4 + r;
                if (row < NN)
                    __builtin_nontemporal_store(acc[mi][ni][r] + bb,
                                                out + (size_t)row * 256 + col);
            }
        }
    }
}

extern "C" void kernel_launch(void* const* d_in, const int* in_sizes, int n_in,
                              void* d_out, int out_size, void* d_ws, size_t ws_size,
                              hipStream_t stream) {
    const float* x   = (const float*)d_in[0];
    const int*   ei  = (const int*)d_in[1];
    const float* ew  = (const float*)d_in[2];
    const float* Wl0 = (const float*)d_in[3];
    const float* Wr0 = (const float*)d_in[4];
    const float* b0  = (const float*)d_in[5];
    const float* Wl1 = (const float*)d_in[6];
    const float* Wr1 = (const float*)d_in[7];
    const float* b1  = (const float*)d_in[8];
    float* out = (float*)d_out;

    const int* src = ei;
    const int* dst = ei + NE;

    // ws layout (bytes), total ~58.6 MB:
    //   0        dinv  f32[50000]
    //   204800   cnt   int[50000]; bsum @ cnt+50048 (both zeroed by one memset)
    //   409600   rp    int[50001]
    //   614400   epk   int2[800000]
    //   7014400  Bt0   bf16[256*256]
    //   7145472  Bt1   bf16[256*512]
    //   7407616  h1b   bf16[50000*256]; rank int[800000] aliases head (dead
    //            after bucket, before mfma0 writes h1b)
    //   33007616 aggb  bf16[50000*256]; layer0: agg=[NN][128], xb in 2nd half
    char* ws = (char*)d_ws;
    float*          dinv = (float*)(ws + 0);
    int*            cnt  = (int*)(ws + 204800);
    int*            bsum = cnt + 50048;
    int*            rp   = (int*)(ws + 409600);
    int2*           epk  = (int2*)(ws + 614400);
    unsigned short* Bt0  = (unsigned short*)(ws + 7014400);
    unsigned short* Bt1  = (unsigned short*)(ws + 7145472);
    unsigned short* h1b  = (unsigned short*)(ws + 7407616);
    int*            rank = (int*)h1b;
    unsigned short* aggb = (unsigned short*)(ws + 33007616);
    unsigned short* xb   = aggb + (size_t)NN * 128;

    hipMemsetAsync(cnt, 0, 204800, stream);  // zeros cnt + bsum
    k_preph<<<PH_HIST + PH_BT0 + PH_BT1 + PH_XB, 256, 0, stream>>>(
        x, Wl0, Wr0, Wl1, Wr1, dst, cnt, rank, Bt0, Bt1, xb);
    k_scanf<<<49, 1024, 0, stream>>>(cnt, bsum, rp, dinv);
    k_bucket<<<(NE + 1023) / 1024, 256, 0, stream>>>(src, dst, ew, rank, rp, epk);

    // layer 0
    k_gather0<<<(NN * 64 + 255) / 256, 256, 0, stream>>>(xb, rp, (const int2*)epk, dinv, aggb);
    dim3 g((NN + 127) / 128, 2);
    k_mfma<128, false, true><<<g, 256, 0, stream>>>(aggb, xb, Bt0, b0, h1b);
    // layer 1 (fused gather + GEMM)
    k_fused1<<<(NN + 127) / 128, 512, 0, stream>>>(h1b, rp, (const int2*)epk, dinv, Bt1, b1, out);
}

// Round 4
// 315.696 us; speedup vs baseline: 1.2881x; 1.2881x over previous
//
#include <hip/hip_runtime.h>

// GraphSAGE 2-layer. N=50000, E=800000, 128 -> 256 -> 256.
// Round 13: revert round-12 fusion (gather starved of wave concurrency:
// 3128 waves -> 1.4 TB/s fabric vs 3.75 needed; k_fused1=183us). Back to
// round-11 structure. One change: k_mfma2 = 512-thread, 8-wave GEMM with a
// 128x256 (full-N) tile so A (agg+self) is read ONCE per layer instead of
// twice (grid was N-split x2). Saves ~77MB of serial-chain fabric traffic.

#define NN 50000
#define NE 800000

typedef __bf16 v8bf __attribute__((ext_vector_type(8)));
typedef float v4f __attribute__((ext_vector_type(4)));
typedef float nf4 __attribute__((ext_vector_type(4)));
typedef unsigned nu2 __attribute__((ext_vector_type(2)));

__device__ __forceinline__ unsigned short f2b(float f) {
    unsigned u = __float_as_uint(f);
    return (unsigned short)((u + 0x7FFFu + ((u >> 16) & 1u)) >> 16);
}
__device__ __forceinline__ float b2f(unsigned short h) {
    return __uint_as_float(((unsigned)h) << 16);
}
__device__ __forceinline__ unsigned pack2(float a, float b) {
    return (unsigned)f2b(a) | ((unsigned)f2b(b) << 16);
}

// Fused hist + prep. Sections by blockIdx (256 threads each), hist FIRST so
// its atomic-bound phase overlaps the streaming casts behind it:
//   [0,782)            hist: cnt[dst]++ and rank[e] = old count. 1024 e/blk.
//   [782,1038)         Bt0 cast
//   [1038,1550)        Bt1 cast
//   [1550,7800)        x -> bf16 (1.6M float4)
#define PH_HIST 782
#define PH_BT0 256
#define PH_BT1 512
#define PH_XB  6250
__global__ __launch_bounds__(256) void k_preph(const float* __restrict__ x,
                                               const float* __restrict__ Wl0,
                                               const float* __restrict__ Wr0,
                                               const float* __restrict__ Wl1,
                                               const float* __restrict__ Wr1,
                                               const int* __restrict__ dst,
                                               int* __restrict__ cnt,
                                               int* __restrict__ rank,
                                               unsigned short* __restrict__ Bt0,
                                               unsigned short* __restrict__ Bt1,
                                               unsigned short* __restrict__ xb) {
    int b = blockIdx.x;
    int tid = threadIdx.x;
    if (b < PH_HIST) {
        int e = b * 1024 + tid;                         // 4 edges/thread, stride 256
        if (e + 768 < NE) {
            int d0 = __builtin_nontemporal_load(dst + e);
            int d1 = __builtin_nontemporal_load(dst + e + 256);
            int d2 = __builtin_nontemporal_load(dst + e + 512);
            int d3 = __builtin_nontemporal_load(dst + e + 768);
            int p0 = atomicAdd(&cnt[d0], 1);
            int p1 = atomicAdd(&cnt[d1], 1);
            int p2 = atomicAdd(&cnt[d2], 1);
            int p3 = atomicAdd(&cnt[d3], 1);
            __builtin_nontemporal_store(p0, rank + e);
            __builtin_nontemporal_store(p1, rank + e + 256);
            __builtin_nontemporal_store(p2, rank + e + 512);
            __builtin_nontemporal_store(p3, rank + e + 768);
        } else {
#pragma unroll
            for (int i = 0; i < 4; ++i) {
                int ee = e + i * 256;
                if (ee < NE) {
                    int d = __builtin_nontemporal_load(dst + ee);
                    int pos = atomicAdd(&cnt[d], 1);
                    __builtin_nontemporal_store(pos, rank + ee);
                }
            }
        }
    } else if (b < PH_HIST + PH_BT0) {
        int idx = (b - PH_HIST) * 256 + tid;            // [0, 65536)
        int n = idx >> 8, k = idx & 255;
        float v = (k < 128) ? Wl0[(size_t)k * 256 + n] : Wr0[(size_t)(k - 128) * 256 + n];
        Bt0[idx] = f2b(v);
    } else if (b < PH_HIST + PH_BT0 + PH_BT1) {
        int idx = (b - PH_HIST - PH_BT0) * 256 + tid;   // [0, 131072)
        int n = idx >> 9, k = idx & 511;
        float v = (k < 256) ? Wl1[(size_t)k * 256 + n] : Wr1[(size_t)(k - 256) * 256 + n];
        Bt1[idx] = f2b(v);
    } else {
        int i4 = (b - PH_HIST - PH_BT0 - PH_BT1) * 256 + tid;  // [0, 1.6M)
        nf4 v = __builtin_nontemporal_load((const nf4*)x + i4);
        nu2 o;
        o.x = pack2(v.x, v.y);
        o.y = pack2(v.z, v.w);
        *((nu2*)xb + i4) = o;
    }
}

// Fused scan: 49 blocks x 1024. Per-block LDS scan; chunk sums published via
// atomicExch flags (value+1), thread 0 spin-accumulates earlier chunks.
// 49 blocks <= 256 CUs: all co-resident.
__global__ __launch_bounds__(1024) void k_scanf(const int* __restrict__ cnt,
                                                int* __restrict__ bsum,
                                                int* __restrict__ rp,
                                                float* __restrict__ dinv) {
    __shared__ int tmp[1024];
    __shared__ int s_off;
    const int b = blockIdx.x, tid = threadIdx.x;
    const int gid = b * 1024 + tid;
    int v = (gid < NN) ? cnt[gid] : 0;
    tmp[tid] = v;
    __syncthreads();
    for (int off = 1; off < 1024; off <<= 1) {
        int t = (tid >= off) ? tmp[tid - off] : 0;
        __syncthreads();
        tmp[tid] += t;
        __syncthreads();
    }
    if (tid == 1023) atomicExch(&bsum[b], tmp[1023] + 1);   // publish (nonzero)
    if (tid == 0) {
        int off = 0;
        for (int i = 0; i < b; ++i) {
            int val;
            while ((val = atomicAdd(&bsum[i], 0)) == 0) {}
            off += val - 1;
        }
        s_off = off;
    }
    __syncthreads();
    if (gid < NN) {
        rp[gid] = tmp[tid] - v + s_off;
        dinv[gid] = 1.0f / fmaxf((float)v, 1.0f);
    }
    if (gid == 0) rp[NN] = NE;
}

// Atomic-free bucket: pos = rp[dst] + rank. 4 edges/thread, ILP.
__global__ __launch_bounds__(256) void k_bucket(const int* __restrict__ src,
                                                const int* __restrict__ dst,
                                                const float* __restrict__ ew,
                                                const int* __restrict__ rank,
                                                const int* __restrict__ rp,
                                                int2* __restrict__ epk) {
    int base = blockIdx.x * 1024 + threadIdx.x;
#pragma unroll
    for (int i = 0; i < 4; ++i) {
        int e = base + i * 256;
        if (e < NE) {
            int d = __builtin_nontemporal_load(dst + e);
            int r = __builtin_nontemporal_load(rank + e);
            int s = __builtin_nontemporal_load(src + e);
            float w = __builtin_nontemporal_load(ew + e);
            epk[rp[d] + r] = make_int2(s, __float_as_int(w));
        }
    }
}

// gather0: xb bf16 [NN][128] -> aggb bf16 [NN][128] (scaled by dinv).
// 1 wave/node; edge metadata batch-loaded (lane L holds epk[b+L]) + shfl.
// 8-edge batches: 8 independent row loads in flight per wave.
__global__ __launch_bounds__(256) void k_gather0(const unsigned short* __restrict__ xb,
                                                 const int* __restrict__ rp,
                                                 const int2* __restrict__ epk,
                                                 const float* __restrict__ dinv,
                                                 unsigned short* __restrict__ aggb) {
    int wid = (blockIdx.x * 256 + threadIdx.x) >> 6;
    int lane = threadIdx.x & 63;
    if (wid >= NN) return;
    int beg = rp[wid], end = rp[wid + 1];
    float di = dinv[wid];
    float ax = 0.f, ay = 0.f;
    for (int b = beg; b < end; b += 64) {
        int n = min(end - b, 64);
        int2 pk = epk[b + min(lane, n - 1)];
        int j = 0;
        for (; j + 7 < n; j += 8) {
            int s[8];
#pragma unroll
            for (int i = 0; i < 8; ++i) s[i] = __shfl(pk.x, j + i);
            unsigned u[8];
#pragma unroll
            for (int i = 0; i < 8; ++i)
                u[i] = *(const unsigned*)(xb + (size_t)s[i] * 128 + lane * 2);
            float w[8];
#pragma unroll
            for (int i = 0; i < 8; ++i) w[i] = __int_as_float(__shfl(pk.y, j + i));
#pragma unroll
            for (int i = 0; i < 8; ++i) {
                ax += w[i] * b2f((unsigned short)(u[i] & 0xFFFF));
                ay += w[i] * b2f((unsigned short)(u[i] >> 16));
            }
        }
        for (; j + 3 < n; j += 4) {
            int s0 = __shfl(pk.x, j + 0), s1 = __shfl(pk.x, j + 1);
            int s2 = __shfl(pk.x, j + 2), s3 = __shfl(pk.x, j + 3);
            unsigned u0 = *(const unsigned*)(xb + (size_t)s0 * 128 + lane * 2);
            unsigned u1 = *(const unsigned*)(xb + (size_t)s1 * 128 + lane * 2);
            unsigned u2 = *(const unsigned*)(xb + (size_t)s2 * 128 + lane * 2);
            unsigned u3 = *(const unsigned*)(xb + (size_t)s3 * 128 + lane * 2);
            float w0 = __int_as_float(__shfl(pk.y, j + 0));
            float w1 = __int_as_float(__shfl(pk.y, j + 1));
            float w2 = __int_as_float(__shfl(pk.y, j + 2));
            float w3 = __int_as_float(__shfl(pk.y, j + 3));
            ax += w0 * b2f((unsigned short)(u0 & 0xFFFF)) + w1 * b2f((unsigned short)(u1 & 0xFFFF))
                + w2 * b2f((unsigned short)(u2 & 0xFFFF)) + w3 * b2f((unsigned short)(u3 & 0xFFFF));
            ay += w0 * b2f((unsigned short)(u0 >> 16)) + w1 * b2f((unsigned short)(u1 >> 16))
                + w2 * b2f((unsigned short)(u2 >> 16)) + w3 * b2f((unsigned short)(u3 >> 16));
        }
        for (; j < n; ++j) {
            int s = __shfl(pk.x, j);
            float w = __int_as_float(__shfl(pk.y, j));
            unsigned u = *(const unsigned*)(xb + (size_t)s * 128 + lane * 2);
            ax += w * b2f((unsigned short)(u & 0xFFFF));
            ay += w * b2f((unsigned short)(u >> 16));
        }
    }
    __builtin_nontemporal_store(pack2(ax * di, ay * di),
                                (unsigned*)(aggb + (size_t)wid * 128 + lane * 2));
}

// gather1: h1 bf16 [NN][256] -> aggb bf16 [NN][256]. 1 wave/node, 4 ch/lane.
// 8-edge batches: 8 independent uint2 row loads in flight per wave.
__global__ __launch_bounds__(256) void k_gather1(const unsigned short* __restrict__ h,
                                                 const int* __restrict__ rp,
                                                 const int2* __restrict__ epk,
                                                 const float* __restrict__ dinv,
                                                 unsigned short* __restrict__ aggb) {
    int wid = (blockIdx.x * 256 + threadIdx.x) >> 6;
    int lane = threadIdx.x & 63;
    if (wid >= NN) return;
    int beg = rp[wid], end = rp[wid + 1];
    float di = dinv[wid];
    float a0 = 0.f, a1 = 0.f, a2 = 0.f, a3 = 0.f;
    for (int b = beg; b < end; b += 64) {
        int n = min(end - b, 64);
        int2 pk = epk[b + min(lane, n - 1)];
        int j = 0;
        for (; j + 7 < n; j += 8) {
            int s[8];
#pragma unroll
            for (int i = 0; i < 8; ++i) s[i] = __shfl(pk.x, j + i);
            uint2 u[8];
#pragma unroll
            for (int i = 0; i < 8; ++i)
                u[i] = *(const uint2*)(h + (size_t)s[i] * 256 + lane * 4);
            float w[8];
#pragma unroll
            for (int i = 0; i < 8; ++i) w[i] = __int_as_float(__shfl(pk.y, j + i));
#pragma unroll
            for (int i = 0; i < 8; ++i) {
                a0 += w[i] * b2f((unsigned short)(u[i].x & 0xFFFF));
                a1 += w[i] * b2f((unsigned short)(u[i].x >> 16));
                a2 += w[i] * b2f((unsigned short)(u[i].y & 0xFFFF));
                a3 += w[i] * b2f((unsigned short)(u[i].y >> 16));
            }
        }
        for (; j + 3 < n; j += 4) {
            int s0 = __shfl(pk.x, j + 0), s1 = __shfl(pk.x, j + 1);
            int s2 = __shfl(pk.x, j + 2), s3 = __shfl(pk.x, j + 3);
            uint2 u0 = *(const uint2*)(h + (size_t)s0 * 256 + lane * 4);
            uint2 u1 = *(const uint2*)(h + (size_t)s1 * 256 + lane * 4);
            uint2 u2 = *(const uint2*)(h + (size_t)s2 * 256 + lane * 4);
            uint2 u3 = *(const uint2*)(h + (size_t)s3 * 256 + lane * 4);
            float w0 = __int_as_float(__shfl(pk.y, j + 0));
            float w1 = __int_as_float(__shfl(pk.y, j + 1));
            float w2 = __int_as_float(__shfl(pk.y, j + 2));
            float w3 = __int_as_float(__shfl(pk.y, j + 3));
            a0 += w0 * b2f((unsigned short)(u0.x & 0xFFFF)) + w1 * b2f((unsigned short)(u1.x & 0xFFFF))
                + w2 * b2f((unsigned short)(u2.x & 0xFFFF)) + w3 * b2f((unsigned short)(u3.x & 0xFFFF));
            a1 += w0 * b2f((unsigned short)(u0.x >> 16)) + w1 * b2f((unsigned short)(u1.x >> 16))
                + w2 * b2f((unsigned short)(u2.x >> 16)) + w3 * b2f((unsigned short)(u3.x >> 16));
            a2 += w0 * b2f((unsigned short)(u0.y & 0xFFFF)) + w1 * b2f((unsigned short)(u1.y & 0xFFFF))
                + w2 * b2f((unsigned short)(u2.y & 0xFFFF)) + w3 * b2f((unsigned short)(u3.y & 0xFFFF));
            a3 += w0 * b2f((unsigned short)(u0.y >> 16)) + w1 * b2f((unsigned short)(u1.y >> 16))
                + w2 * b2f((unsigned short)(u2.y >> 16)) + w3 * b2f((unsigned short)(u3.y >> 16));
        }
        for (; j < n; ++j) {
            int s = __shfl(pk.x, j);
            float w = __int_as_float(__shfl(pk.y, j));
            uint2 u = *(const uint2*)(h + (size_t)s * 256 + lane * 4);
            a0 += w * b2f((unsigned short)(u.x & 0xFFFF));
            a1 += w * b2f((unsigned short)(u.x >> 16));
            a2 += w * b2f((unsigned short)(u.y & 0xFFFF));
            a3 += w * b2f((unsigned short)(u.y >> 16));
        }
    }
    nu2 o;
    o.x = pack2(a0 * di, a1 * di);
    o.y = pack2(a2 * di, a3 * di);
    __builtin_nontemporal_store(o, (nu2*)(aggb + (size_t)wid * 256 + lane * 4));
}

// MFMA GEMM: C[row, 0:256] = concat(Aagg[row,:], Aself[row,:]) @ Bt^T + bias.
// 128x256 (full-N) tile per block, 512 threads / 8 waves (4M x 2N), each wave
// a 32x128 output (2x8 frags of 16x16x32). A read ONCE from global per layer.
// LDS: As 128x32 (8KB) + Bs 256x32 (16KB) per k-step.
template <int K0, bool OUT_F32, bool RELU>
__global__ __launch_bounds__(512) void k_mfma2(const unsigned short* __restrict__ Aagg,
                                               const unsigned short* __restrict__ Aself,
                                               const unsigned short* __restrict__ Bt,
                                               const float* __restrict__ bias,
                                               void* __restrict__ outp) {
    __shared__ unsigned short As[128 * 32];
    __shared__ unsigned short Bs[256 * 32];
    const int tid = threadIdx.x;
    const int m0 = blockIdx.x * 128;
    const int K = 2 * K0;
    const int lane = tid & 63;
    const int w = tid >> 6;
    const int wr = w >> 1, wc = w & 1;          // 4 M-waves x 2 N-waves
    const int fr = lane & 15, fq = lane >> 4;
    const int srowA = tid >> 2;                  // 0..127
    const int sckA = (tid & 3) * 8;              // k-chunk of 8
    const int srowB = tid >> 1;                  // 0..255
    const int sckB = (tid & 1) * 16;             // two uint4: k and k+8

    v4f acc[2][8];
#pragma unroll
    for (int mi = 0; mi < 2; ++mi)
#pragma unroll
        for (int ni = 0; ni < 8; ++ni)
            acc[mi][ni] = (v4f){0.f, 0.f, 0.f, 0.f};

    for (int k0 = 0; k0 < K; k0 += 32) {
        // register-stage global loads
        const int kkA = k0 + sckA;
        const unsigned short* Asrc = (kkA < K0) ? Aagg : (Aself - K0);
        const int rA = m0 + srowA;
        uint4 av = make_uint4(0, 0, 0, 0);
        if (rA < NN) av = *(const uint4*)(Asrc + (size_t)rA * K0 + kkA);
        uint4 bv0 = *(const uint4*)(Bt + (size_t)srowB * K + k0 + sckB);
        uint4 bv1 = *(const uint4*)(Bt + (size_t)srowB * K + k0 + sckB + 8);

        __syncthreads();
        *(uint4*)(As + srowA * 32 + sckA) = av;
        *(uint4*)(Bs + srowB * 32 + sckB) = bv0;
        *(uint4*)(Bs + srowB * 32 + sckB + 8) = bv1;
        __syncthreads();

        v8bf a[2], b[8];
#pragma unroll
        for (int mi = 0; mi < 2; ++mi)
            a[mi] = *(const v8bf*)(As + (wr * 32 + mi * 16 + fr) * 32 + fq * 8);
#pragma unroll
        for (int ni = 0; ni < 8; ++ni)
            b[ni] = *(const v8bf*)(Bs + (wc * 128 + ni * 16 + fr) * 32 + fq * 8);
#pragma unroll
        for (int mi = 0; mi < 2; ++mi)
#pragma unroll
            for (int ni = 0; ni < 8; ++ni)
                acc[mi][ni] = __builtin_amdgcn_mfma_f32_16x16x32_bf16(a[mi], b[ni], acc[mi][ni], 0, 0, 0);
    }

#pragma unroll
    for (int mi = 0; mi < 2; ++mi) {
#pragma unroll
        for (int ni = 0; ni < 8; ++ni) {
            const int col = wc * 128 + ni * 16 + fr;
            const float bb = bias[col];
#pragma unroll
            for (int r = 0; r < 4; ++r) {
                const int row = m0 + wr * 32 + mi * 16 + fq * 4 + r;
                if (row < NN) {
                    float v = acc[mi][ni][r] + bb;
                    if (RELU) v = fmaxf(v, 0.f);
                    if (OUT_F32)
                        __builtin_nontemporal_store(v, &((float*)outp)[(size_t)row * 256 + col]);
                    else
                        ((unsigned short*)outp)[(size_t)row * 256 + col] = f2b(v);
                }
            }
        }
    }
}

extern "C" void kernel_launch(void* const* d_in, const int* in_sizes, int n_in,
                              void* d_out, int out_size, void* d_ws, size_t ws_size,
                              hipStream_t stream) {
    const float* x   = (const float*)d_in[0];
    const int*   ei  = (const int*)d_in[1];
    const float* ew  = (const float*)d_in[2];
    const float* Wl0 = (const float*)d_in[3];
    const float* Wr0 = (const float*)d_in[4];
    const float* b0  = (const float*)d_in[5];
    const float* Wl1 = (const float*)d_in[6];
    const float* Wr1 = (const float*)d_in[7];
    const float* b1  = (const float*)d_in[8];
    float* out = (float*)d_out;

    const int* src = ei;
    const int* dst = ei + NE;

    // ws layout (bytes), total ~58.6 MB:
    //   0        dinv  f32[50000]
    //   204800   cnt   int[50000]; bsum @ cnt+50048 (both zeroed by one memset)
    //   409600   rp    int[50001]
    //   614400   epk   int2[800000]
    //   7014400  Bt0   bf16[256*256]
    //   7145472  Bt1   bf16[256*512]
    //   7407616  h1b   bf16[50000*256]; rank int[800000] aliases head (dead
    //            after bucket, before mfma0 writes h1b)
    //   33007616 aggb  bf16[50000*256]; layer0: agg=[NN][128], xb in 2nd half
    char* ws = (char*)d_ws;
    float*          dinv = (float*)(ws + 0);
    int*            cnt  = (int*)(ws + 204800);
    int*            bsum = cnt + 50048;
    int*            rp   = (int*)(ws + 409600);
    int2*           epk  = (int2*)(ws + 614400);
    unsigned short* Bt0  = (unsigned short*)(ws + 7014400);
    unsigned short* Bt1  = (unsigned short*)(ws + 7145472);
    unsigned short* h1b  = (unsigned short*)(ws + 7407616);
    int*            rank = (int*)h1b;
    unsigned short* aggb = (unsigned short*)(ws + 33007616);
    unsigned short* xb   = aggb + (size_t)NN * 128;

    hipMemsetAsync(cnt, 0, 204800, stream);  // zeros cnt + bsum
    k_preph<<<PH_HIST + PH_BT0 + PH_BT1 + PH_XB, 256, 0, stream>>>(
        x, Wl0, Wr0, Wl1, Wr1, dst, cnt, rank, Bt0, Bt1, xb);
    k_scanf<<<49, 1024, 0, stream>>>(cnt, bsum, rp, dinv);
    k_bucket<<<(NE + 1023) / 1024, 256, 0, stream>>>(src, dst, ew, rank, rp, epk);

    const int gm = (NN + 127) / 128;
    // layer 0
    k_gather0<<<(NN * 64 + 255) / 256, 256, 0, stream>>>(xb, rp, (const int2*)epk, dinv, aggb);
    k_mfma2<128, false, true><<<gm, 512, 0, stream>>>(aggb, xb, Bt0, b0, h1b);
    // layer 1
    k_gather1<<<(NN * 64 + 255) / 256, 256, 0, stream>>>(h1b, rp, (const int2*)epk, dinv, aggb);
    k_mfma2<256, true, false><<<gm, 512, 0, stream>>>(aggb, h1b, Bt1, b1, out);
}

// Round 5
// 314.051 us; speedup vs baseline: 1.2948x; 1.0052x over previous
//
#include <hip/hip_runtime.h>

// GraphSAGE 2-layer. N=50000, E=800000, 128 -> 256 -> 256.
// Round 14: two independent levers.
//  (1) gather0/gather1 blocks 256->128 thr (2 waves): finer drain/refill
//      granularity; gather BW scales ~linearly with resident waves.
//  (2) hist -> 4 replica histograms (replica=(e>>6)&3, wave-uniform) to cut
//      per-cacheline atomic serialization 4x. scanf sums replicas and emits
//      int4 per-replica bases (rp4); bucket selects by replica. cnt4/rp4/bsum
//      live in dead h1b-head scratch (zero new ws).

#define NN 50000
#define NE 800000

typedef __bf16 v8bf __attribute__((ext_vector_type(8)));
typedef float v4f __attribute__((ext_vector_type(4)));
typedef float nf4 __attribute__((ext_vector_type(4)));
typedef unsigned nu2 __attribute__((ext_vector_type(2)));

__device__ __forceinline__ unsigned short f2b(float f) {
    unsigned u = __float_as_uint(f);
    return (unsigned short)((u + 0x7FFFu + ((u >> 16) & 1u)) >> 16);
}
__device__ __forceinline__ float b2f(unsigned short h) {
    return __uint_as_float(((unsigned)h) << 16);
}
__device__ __forceinline__ unsigned pack2(float a, float b) {
    return (unsigned)f2b(a) | ((unsigned)f2b(b) << 16);
}

// Fused hist + prep. Sections by blockIdx (256 threads each), hist FIRST so
// its atomic-bound phase overlaps the streaming casts behind it:
//   [0,782)            hist: cnt4[rep][dst]++, rank[e]=old. 1024 e/blk.
//   [782,1038)         Bt0 cast
//   [1038,1550)        Bt1 cast
//   [1550,7800)        x -> bf16 (1.6M float4)
#define PH_HIST 782
#define PH_BT0 256
#define PH_BT1 512
#define PH_XB  6250
#define CREP 50048
__global__ __launch_bounds__(256) void k_preph(const float* __restrict__ x,
                                               const float* __restrict__ Wl0,
                                               const float* __restrict__ Wr0,
                                               const float* __restrict__ Wl1,
                                               const float* __restrict__ Wr1,
                                               const int* __restrict__ dst,
                                               int* __restrict__ cnt4,
                                               int* __restrict__ rank,
                                               unsigned short* __restrict__ Bt0,
                                               unsigned short* __restrict__ Bt1,
                                               unsigned short* __restrict__ xb) {
    int b = blockIdx.x;
    int tid = threadIdx.x;
    if (b < PH_HIST) {
        int e = b * 1024 + tid;                         // 4 edges/thread, stride 256
        int* cr = cnt4 + ((tid >> 6) & 3) * CREP;       // replica = (e>>6)&3
        if (e + 768 < NE) {
            int d0 = __builtin_nontemporal_load(dst + e);
            int d1 = __builtin_nontemporal_load(dst + e + 256);
            int d2 = __builtin_nontemporal_load(dst + e + 512);
            int d3 = __builtin_nontemporal_load(dst + e + 768);
            int p0 = atomicAdd(&cr[d0], 1);
            int p1 = atomicAdd(&cr[d1], 1);
            int p2 = atomicAdd(&cr[d2], 1);
            int p3 = atomicAdd(&cr[d3], 1);
            __builtin_nontemporal_store(p0, rank + e);
            __builtin_nontemporal_store(p1, rank + e + 256);
            __builtin_nontemporal_store(p2, rank + e + 512);
            __builtin_nontemporal_store(p3, rank + e + 768);
        } else {
#pragma unroll
            for (int i = 0; i < 4; ++i) {
                int ee = e + i * 256;
                if (ee < NE) {
                    int d = __builtin_nontemporal_load(dst + ee);
                    int pos = atomicAdd(&cr[d], 1);
                    __builtin_nontemporal_store(pos, rank + ee);
                }
            }
        }
    } else if (b < PH_HIST + PH_BT0) {
        int idx = (b - PH_HIST) * 256 + tid;            // [0, 65536)
        int n = idx >> 8, k = idx & 255;
        float v = (k < 128) ? Wl0[(size_t)k * 256 + n] : Wr0[(size_t)(k - 128) * 256 + n];
        Bt0[idx] = f2b(v);
    } else if (b < PH_HIST + PH_BT0 + PH_BT1) {
        int idx = (b - PH_HIST - PH_BT0) * 256 + tid;   // [0, 131072)
        int n = idx >> 9, k = idx & 511;
        float v = (k < 256) ? Wl1[(size_t)k * 256 + n] : Wr1[(size_t)(k - 256) * 256 + n];
        Bt1[idx] = f2b(v);
    } else {
        int i4 = (b - PH_HIST - PH_BT0 - PH_BT1) * 256 + tid;  // [0, 1.6M)
        nf4 v = __builtin_nontemporal_load((const nf4*)x + i4);
        nu2 o;
        o.x = pack2(v.x, v.y);
        o.y = pack2(v.z, v.w);
        *((nu2*)xb + i4) = o;
    }
}

// Fused scan: 49 blocks x 1024. Sums 4 replica counts; per-block LDS scan of
// totals; chunk sums via atomic flags. Emits rp (totals, for gathers), rp4
// (per-replica bases, for bucket), dinv.
__global__ __launch_bounds__(1024) void k_scanf(const int* __restrict__ cnt4,
                                                int* __restrict__ bsum,
                                                int* __restrict__ rp,
                                                int4* __restrict__ rp4,
                                                float* __restrict__ dinv) {
    __shared__ int tmp[1024];
    __shared__ int s_off;
    const int b = blockIdx.x, tid = threadIdx.x;
    const int gid = b * 1024 + tid;
    int c0 = 0, c1 = 0, c2 = 0, c3 = 0;
    if (gid < NN) {
        c0 = cnt4[gid];
        c1 = cnt4[CREP + gid];
        c2 = cnt4[2 * CREP + gid];
        c3 = cnt4[3 * CREP + gid];
    }
    int v = c0 + c1 + c2 + c3;
    tmp[tid] = v;
    __syncthreads();
    for (int off = 1; off < 1024; off <<= 1) {
        int t = (tid >= off) ? tmp[tid - off] : 0;
        __syncthreads();
        tmp[tid] += t;
        __syncthreads();
    }
    if (tid == 1023) atomicExch(&bsum[b], tmp[1023] + 1);   // publish (nonzero)
    if (tid == 0) {
        int off = 0;
        for (int i = 0; i < b; ++i) {
            int val;
            while ((val = atomicAdd(&bsum[i], 0)) == 0) {}
            off += val - 1;
        }
        s_off = off;
    }
    __syncthreads();
    if (gid < NN) {
        int base = tmp[tid] - v + s_off;
        rp[gid] = base;
        rp4[gid] = make_int4(base, base + c0, base + c0 + c1, base + c0 + c1 + c2);
        dinv[gid] = 1.0f / fmaxf((float)v, 1.0f);
    }
    if (gid == 0) rp[NN] = NE;
}

// Atomic-free bucket: pos = rp4[dst].sel(replica) + rank. 4 edges/thread.
__global__ __launch_bounds__(256) void k_bucket(const int* __restrict__ src,
                                                const int* __restrict__ dst,
                                                const float* __restrict__ ew,
                                                const int* __restrict__ rank,
                                                const int4* __restrict__ rp4,
                                                int2* __restrict__ epk) {
    int base = blockIdx.x * 1024 + threadIdx.x;
    int rep = (threadIdx.x >> 6) & 3;                    // == (e>>6)&3 for all i
#pragma unroll
    for (int i = 0; i < 4; ++i) {
        int e = base + i * 256;
        if (e < NE) {
            int d = __builtin_nontemporal_load(dst + e);
            int r = __builtin_nontemporal_load(rank + e);
            int s = __builtin_nontemporal_load(src + e);
            float w = __builtin_nontemporal_load(ew + e);
            int4 q = rp4[d];
            int off = (rep == 0) ? q.x : (rep == 1) ? q.y : (rep == 2) ? q.z : q.w;
            epk[off + r] = make_int2(s, __float_as_int(w));
        }
    }
}

// gather0: xb bf16 [NN][128] -> aggb bf16 [NN][128] (scaled by dinv).
// 1 wave/node, 128-thr blocks (2 waves) for fine drain/refill granularity.
// 8-edge batches: 8 independent row loads in flight per wave.
__global__ __launch_bounds__(128) void k_gather0(const unsigned short* __restrict__ xb,
                                                 const int* __restrict__ rp,
                                                 const int2* __restrict__ epk,
                                                 const float* __restrict__ dinv,
                                                 unsigned short* __restrict__ aggb) {
    int wid = (blockIdx.x * 128 + threadIdx.x) >> 6;
    int lane = threadIdx.x & 63;
    if (wid >= NN) return;
    int beg = rp[wid], end = rp[wid + 1];
    float di = dinv[wid];
    float ax = 0.f, ay = 0.f;
    for (int b = beg; b < end; b += 64) {
        int n = min(end - b, 64);
        int2 pk = epk[b + min(lane, n - 1)];
        int j = 0;
        for (; j + 7 < n; j += 8) {
            int s[8];
#pragma unroll
            for (int i = 0; i < 8; ++i) s[i] = __shfl(pk.x, j + i);
            unsigned u[8];
#pragma unroll
            for (int i = 0; i < 8; ++i)
                u[i] = *(const unsigned*)(xb + (size_t)s[i] * 128 + lane * 2);
            float w[8];
#pragma unroll
            for (int i = 0; i < 8; ++i) w[i] = __int_as_float(__shfl(pk.y, j + i));
#pragma unroll
            for (int i = 0; i < 8; ++i) {
                ax += w[i] * b2f((unsigned short)(u[i] & 0xFFFF));
                ay += w[i] * b2f((unsigned short)(u[i] >> 16));
            }
        }
        for (; j + 3 < n; j += 4) {
            int s0 = __shfl(pk.x, j + 0), s1 = __shfl(pk.x, j + 1);
            int s2 = __shfl(pk.x, j + 2), s3 = __shfl(pk.x, j + 3);
            unsigned u0 = *(const unsigned*)(xb + (size_t)s0 * 128 + lane * 2);
            unsigned u1 = *(const unsigned*)(xb + (size_t)s1 * 128 + lane * 2);
            unsigned u2 = *(const unsigned*)(xb + (size_t)s2 * 128 + lane * 2);
            unsigned u3 = *(const unsigned*)(xb + (size_t)s3 * 128 + lane * 2);
            float w0 = __int_as_float(__shfl(pk.y, j + 0));
            float w1 = __int_as_float(__shfl(pk.y, j + 1));
            float w2 = __int_as_float(__shfl(pk.y, j + 2));
            float w3 = __int_as_float(__shfl(pk.y, j + 3));
            ax += w0 * b2f((unsigned short)(u0 & 0xFFFF)) + w1 * b2f((unsigned short)(u1 & 0xFFFF))
                + w2 * b2f((unsigned short)(u2 & 0xFFFF)) + w3 * b2f((unsigned short)(u3 & 0xFFFF));
            ay += w0 * b2f((unsigned short)(u0 >> 16)) + w1 * b2f((unsigned short)(u1 >> 16))
                + w2 * b2f((unsigned short)(u2 >> 16)) + w3 * b2f((unsigned short)(u3 >> 16));
        }
        for (; j < n; ++j) {
            int s = __shfl(pk.x, j);
            float w = __int_as_float(__shfl(pk.y, j));
            unsigned u = *(const unsigned*)(xb + (size_t)s * 128 + lane * 2);
            ax += w * b2f((unsigned short)(u & 0xFFFF));
            ay += w * b2f((unsigned short)(u >> 16));
        }
    }
    __builtin_nontemporal_store(pack2(ax * di, ay * di),
                                (unsigned*)(aggb + (size_t)wid * 128 + lane * 2));
}

// gather1: h1 bf16 [NN][256] -> aggb bf16 [NN][256]. 1 wave/node, 4 ch/lane.
// 128-thr blocks (2 waves). 8-edge batches.
__global__ __launch_bounds__(128) void k_gather1(const unsigned short* __restrict__ h,
                                                 const int* __restrict__ rp,
                                                 const int2* __restrict__ epk,
                                                 const float* __restrict__ dinv,
                                                 unsigned short* __restrict__ aggb) {
    int wid = (blockIdx.x * 128 + threadIdx.x) >> 6;
    int lane = threadIdx.x & 63;
    if (wid >= NN) return;
    int beg = rp[wid], end = rp[wid + 1];
    float di = dinv[wid];
    float a0 = 0.f, a1 = 0.f, a2 = 0.f, a3 = 0.f;
    for (int b = beg; b < end; b += 64) {
        int n = min(end - b, 64);
        int2 pk = epk[b + min(lane, n - 1)];
        int j = 0;
        for (; j + 7 < n; j += 8) {
            int s[8];
#pragma unroll
            for (int i = 0; i < 8; ++i) s[i] = __shfl(pk.x, j + i);
            uint2 u[8];
#pragma unroll
            for (int i = 0; i < 8; ++i)
                u[i] = *(const uint2*)(h + (size_t)s[i] * 256 + lane * 4);
            float w[8];
#pragma unroll
            for (int i = 0; i < 8; ++i) w[i] = __int_as_float(__shfl(pk.y, j + i));
#pragma unroll
            for (int i = 0; i < 8; ++i) {
                a0 += w[i] * b2f((unsigned short)(u[i].x & 0xFFFF));
                a1 += w[i] * b2f((unsigned short)(u[i].x >> 16));
                a2 += w[i] * b2f((unsigned short)(u[i].y & 0xFFFF));
                a3 += w[i] * b2f((unsigned short)(u[i].y >> 16));
            }
        }
        for (; j + 3 < n; j += 4) {
            int s0 = __shfl(pk.x, j + 0), s1 = __shfl(pk.x, j + 1);
            int s2 = __shfl(pk.x, j + 2), s3 = __shfl(pk.x, j + 3);
            uint2 u0 = *(const uint2*)(h + (size_t)s0 * 256 + lane * 4);
            uint2 u1 = *(const uint2*)(h + (size_t)s1 * 256 + lane * 4);
            uint2 u2 = *(const uint2*)(h + (size_t)s2 * 256 + lane * 4);
            uint2 u3 = *(const uint2*)(h + (size_t)s3 * 256 + lane * 4);
            float w0 = __int_as_float(__shfl(pk.y, j + 0));
            float w1 = __int_as_float(__shfl(pk.y, j + 1));
            float w2 = __int_as_float(__shfl(pk.y, j + 2));
            float w3 = __int_as_float(__shfl(pk.y, j + 3));
            a0 += w0 * b2f((unsigned short)(u0.x & 0xFFFF)) + w1 * b2f((unsigned short)(u1.x & 0xFFFF))
                + w2 * b2f((unsigned short)(u2.x & 0xFFFF)) + w3 * b2f((unsigned short)(u3.x & 0xFFFF));
            a1 += w0 * b2f((unsigned short)(u0.x >> 16)) + w1 * b2f((unsigned short)(u1.x >> 16))
                + w2 * b2f((unsigned short)(u2.x >> 16)) + w3 * b2f((unsigned short)(u3.x >> 16));
            a2 += w0 * b2f((unsigned short)(u0.y & 0xFFFF)) + w1 * b2f((unsigned short)(u1.y & 0xFFFF))
                + w2 * b2f((unsigned short)(u2.y & 0xFFFF)) + w3 * b2f((unsigned short)(u3.y & 0xFFFF));
            a3 += w0 * b2f((unsigned short)(u0.y >> 16)) + w1 * b2f((unsigned short)(u1.y >> 16))
                + w2 * b2f((unsigned short)(u2.y >> 16)) + w3 * b2f((unsigned short)(u3.y >> 16));
        }
        for (; j < n; ++j) {
            int s = __shfl(pk.x, j);
            float w = __int_as_float(__shfl(pk.y, j));
            uint2 u = *(const uint2*)(h + (size_t)s * 256 + lane * 4);
            a0 += w * b2f((unsigned short)(u.x & 0xFFFF));
            a1 += w * b2f((unsigned short)(u.x >> 16));
            a2 += w * b2f((unsigned short)(u.y & 0xFFFF));
            a3 += w * b2f((unsigned short)(u.y >> 16));
        }
    }
    nu2 o;
    o.x = pack2(a0 * di, a1 * di);
    o.y = pack2(a2 * di, a3 * di);
    __builtin_nontemporal_store(o, (nu2*)(aggb + (size_t)wid * 256 + lane * 4));
}

// MFMA GEMM: C[row, 0:256] = concat(Aagg[row,:], Aself[row,:]) @ Bt^T + bias.
// 128x256 (full-N) tile per block, 512 threads / 8 waves (4M x 2N).
template <int K0, bool OUT_F32, bool RELU>
__global__ __launch_bounds__(512) void k_mfma2(const unsigned short* __restrict__ Aagg,
                                               const unsigned short* __restrict__ Aself,
                                               const unsigned short* __restrict__ Bt,
                                               const float* __restrict__ bias,
                                               void* __restrict__ outp) {
    __shared__ unsigned short As[128 * 32];
    __shared__ unsigned short Bs[256 * 32];
    const int tid = threadIdx.x;
    const int m0 = blockIdx.x * 128;
    const int K = 2 * K0;
    const int lane = tid & 63;
    const int w = tid >> 6;
    const int wr = w >> 1, wc = w & 1;          // 4 M-waves x 2 N-waves
    const int fr = lane & 15, fq = lane >> 4;
    const int srowA = tid >> 2;                  // 0..127
    const int sckA = (tid & 3) * 8;              // k-chunk of 8
    const int srowB = tid >> 1;                  // 0..255
    const int sckB = (tid & 1) * 16;             // two uint4: k and k+8

    v4f acc[2][8];
#pragma unroll
    for (int mi = 0; mi < 2; ++mi)
#pragma unroll
        for (int ni = 0; ni < 8; ++ni)
            acc[mi][ni] = (v4f){0.f, 0.f, 0.f, 0.f};

    for (int k0 = 0; k0 < K; k0 += 32) {
        // register-stage global loads
        const int kkA = k0 + sckA;
        const unsigned short* Asrc = (kkA < K0) ? Aagg : (Aself - K0);
        const int rA = m0 + srowA;
        uint4 av = make_uint4(0, 0, 0, 0);
        if (rA < NN) av = *(const uint4*)(Asrc + (size_t)rA * K0 + kkA);
        uint4 bv0 = *(const uint4*)(Bt + (size_t)srowB * K + k0 + sckB);
        uint4 bv1 = *(const uint4*)(Bt + (size_t)srowB * K + k0 + sckB + 8);

        __syncthreads();
        *(uint4*)(As + srowA * 32 + sckA) = av;
        *(uint4*)(Bs + srowB * 32 + sckB) = bv0;
        *(uint4*)(Bs + srowB * 32 + sckB + 8) = bv1;
        __syncthreads();

        v8bf a[2], b[8];
#pragma unroll
        for (int mi = 0; mi < 2; ++mi)
            a[mi] = *(const v8bf*)(As + (wr * 32 + mi * 16 + fr) * 32 + fq * 8);
#pragma unroll
        for (int ni = 0; ni < 8; ++ni)
            b[ni] = *(const v8bf*)(Bs + (wc * 128 + ni * 16 + fr) * 32 + fq * 8);
#pragma unroll
        for (int mi = 0; mi < 2; ++mi)
#pragma unroll
            for (int ni = 0; ni < 8; ++ni)
                acc[mi][ni] = __builtin_amdgcn_mfma_f32_16x16x32_bf16(a[mi], b[ni], acc[mi][ni], 0, 0, 0);
    }

#pragma unroll
    for (int mi = 0; mi < 2; ++mi) {
#pragma unroll
        for (int ni = 0; ni < 8; ++ni) {
            const int col = wc * 128 + ni * 16 + fr;
            const float bb = bias[col];
#pragma unroll
            for (int r = 0; r < 4; ++r) {
                const int row = m0 + wr * 32 + mi * 16 + fq * 4 + r;
                if (row < NN) {
                    float v = acc[mi][ni][r] + bb;
                    if (RELU) v = fmaxf(v, 0.f);
                    if (OUT_F32)
                        __builtin_nontemporal_store(v, &((float*)outp)[(size_t)row * 256 + col]);
                    else
                        ((unsigned short*)outp)[(size_t)row * 256 + col] = f2b(v);
                }
            }
        }
    }
}

extern "C" void kernel_launch(void* const* d_in, const int* in_sizes, int n_in,
                              void* d_out, int out_size, void* d_ws, size_t ws_size,
                              hipStream_t stream) {
    const float* x   = (const float*)d_in[0];
    const int*   ei  = (const int*)d_in[1];
    const float* ew  = (const float*)d_in[2];
    const float* Wl0 = (const float*)d_in[3];
    const float* Wr0 = (const float*)d_in[4];
    const float* b0  = (const float*)d_in[5];
    const float* Wl1 = (const float*)d_in[6];
    const float* Wr1 = (const float*)d_in[7];
    const float* b1  = (const float*)d_in[8];
    float* out = (float*)d_out;

    const int* src = ei;
    const int* dst = ei + NE;

    // ws layout (bytes), total ~58.6 MB (unchanged):
    //   0        dinv  f32[50000]
    //   204800   (old cnt region, now unused)
    //   409600   rp    int[50001]
    //   614400   epk   int2[800000]
    //   7014400  Bt0   bf16[256*256]
    //   7145472  Bt1   bf16[256*512]
    //   7407616  h1b   bf16[50000*256]; head aliases scratch dead before
    //            mfma0 writes h1b: rank int[800000] @ +0 (3.2MB),
    //            cnt4 int[4*50048]+bsum @ +3,200,000, rp4 int4[50000]
    //            @ +4,224,000.
    //   33007616 aggb  bf16[50000*256]; layer0: agg=[NN][128], xb in 2nd half
    char* ws = (char*)d_ws;
    float*          dinv = (float*)(ws + 0);
    int*            rp   = (int*)(ws + 409600);
    int2*           epk  = (int2*)(ws + 614400);
    unsigned short* Bt0  = (unsigned short*)(ws + 7014400);
    unsigned short* Bt1  = (unsigned short*)(ws + 7145472);
    unsigned short* h1b  = (unsigned short*)(ws + 7407616);
    int*            rank = (int*)h1b;
    int*            cnt4 = (int*)((char*)h1b + 3200000);
    int*            bsum = cnt4 + 4 * CREP;
    int4*           rp4  = (int4*)((char*)h1b + 4224000);
    unsigned short* aggb = (unsigned short*)(ws + 33007616);
    unsigned short* xb   = aggb + (size_t)NN * 128;

    hipMemsetAsync(cnt4, 0, 4 * CREP * 4 + 256, stream);  // zeros cnt4 + bsum
    k_preph<<<PH_HIST + PH_BT0 + PH_BT1 + PH_XB, 256, 0, stream>>>(
        x, Wl0, Wr0, Wl1, Wr1, dst, cnt4, rank, Bt0, Bt1, xb);
    k_scanf<<<49, 1024, 0, stream>>>(cnt4, bsum, rp, rp4, dinv);
    k_bucket<<<(NE + 1023) / 1024, 256, 0, stream>>>(src, dst, ew, rank, rp4, epk);

    const int gm = (NN + 127) / 128;
    const int gg = (NN * 64 + 127) / 128;
    // layer 0
    k_gather0<<<gg, 128, 0, stream>>>(xb, rp, (const int2*)epk, dinv, aggb);
    k_mfma2<128, false, true><<<gm, 512, 0, stream>>>(aggb, xb, Bt0, b0, h1b);
    // layer 1
    k_gather1<<<gg, 128, 0, stream>>>(h1b, rp, (const int2*)epk, dinv, aggb);
    k_mfma2<256, true, false><<<gm, 512, 0, stream>>>(aggb, h1b, Bt1, b1, out);
}